// Round 2
// 161.220 us; speedup vs baseline: 1.0147x; 1.0147x over previous
//
#include <hip/hip_runtime.h>

#define E_EDGES 20000
#define D_DIM   128
#define NBA     136       // W2/b2 repack blocks: 128 W2 + 1 bias + 7 zero (prefetch pad)
#define SLAB_B  21504     // per-block hidden slab: 80 edges x 264B (132 h fp16 + pad)

typedef _Float16 f16x8 __attribute__((ext_vector_type(8)));
typedef _Float16 f16x4 __attribute__((ext_vector_type(4)));
typedef _Float16 f16x2 __attribute__((ext_vector_type(2)));
typedef float    floatx4 __attribute__((ext_vector_type(4)));

union F8 { f16x8 v; f16x2 h2[4]; unsigned int u[4]; };
union F4 { f16x4 v; f16x2 h2[2]; unsigned int u[2]; };

__device__ __forceinline__ unsigned short f32_to_f16(float f) {
    _Float16 h = (_Float16)f;
    return __builtin_bit_cast(unsigned short, h);
}

// ---------------------------------------------------------------------------
// prep_w2: repack h-slice of W2 (h==128: b2; h>128: zeros) into fragment-major
// fp16 bpf. cidx = ch*512 + jq*128 + nt*64 + ll; chunk elem j: B_h[k][col],
// col = 32ch+16nt+(ll&15), k = 32jq+8*(ll>>4)+j. One h-slice per block.
// This is the ONLY remaining prep: hidden-MLP and h_w cast are fused into
// edge_main (prep parts B/C deleted — they accounted for the unexplained
// ~81 us gap candidate; if prep is still slow it is now isolated here).
// ---------------------------------------------------------------------------
__global__ __launch_bounds__(256) void prep_w2(
    const float* __restrict__ W2, const float* __restrict__ b2,
    uint4* __restrict__ bpf)
{
    __shared__ __align__(16) unsigned short tile[17408];   // [col][136]
    const int h = blockIdx.x;
    const int t = threadIdx.x;

    if (h < 129) {
        const float* src = (h < 128) ? (W2 + (size_t)h * (D_DIM * D_DIM)) : b2;
        #pragma unroll
        for (int r = 0; r < 16; ++r) {
            const float4 v = ((const float4*)src)[r * 256 + t];
            int c   = (r * 256 + t) * 4;
            int col = c >> 7;
            int k   = c & 127;
            unsigned int u0 = f32_to_f16(v.x) | ((unsigned int)f32_to_f16(v.y) << 16);
            unsigned int u1 = f32_to_f16(v.z) | ((unsigned int)f32_to_f16(v.w) << 16);
            *(uint2*)&tile[col * 136 + k] = make_uint2(u0, u1);
        }
        __syncthreads();
        #pragma unroll
        for (int r2 = 0; r2 < 8; ++r2) {
            int cidx = r2 * 256 + t;
            int ll = cidx & 63;
            int nt = (cidx >> 6) & 1;
            int jq = (cidx >> 7) & 3;
            int ch = (cidx >> 9) & 3;
            int col = 32 * ch + 16 * nt + (ll & 15);
            int k0  = 32 * jq + 8 * (ll >> 4);
            bpf[(size_t)h * 2048 + cidx] = *(const uint4*)&tile[col * 136 + k0];
        }
    } else {
        // zero-fill pad slices so prefetch reads never feed NaN garbage into MFMA
        #pragma unroll
        for (int r2 = 0; r2 < 8; ++r2)
            bpf[(size_t)h * 2048 + r2 * 256 + t] = make_uint4(0, 0, 0, 0);
    }
}

// ---------------------------------------------------------------------------
// Main (Z-GEMM v5, fully fused): 500 blocks x 256 threads.
// Block = 80 edges x 64 cols x 128 j. ch2 = bx&1 is XCD-parity-pinned
// (2.23 MB B working set per XCD L2); eg = bx>>1 in [0,250).
// Wave = j-quarter jq: per h, one A-scale (perm + 4 pk_mul per m) now feeds
// FOUR MFMAs (was two): MFMA-pipe work per wave-h ~388 cyc vs ~60 VALU cyc,
// so a single wave keeps the matrix pipe busy; 2 blocks/CU fill the gaps.
// Fused prologue: (1) hidden = relu(ef@W1+b1) via ONE mfma_f32_16x16x16f16
// per (m,nn) (K=16 = edge_dim exactly) written to the LDS slab fp16 [80][132];
// (2) h_w fp32 loaded + cast to resident fp16 A-source registers.
// This deletes prep parts B/C (hslab + hwb workspace round-trips) entirely.
// Epilogue: jq partials reduced in-block via LDS (reuse slab), coalesced
// stores, no atomics. C/D layout: col = lane&15, row = 4*(lane>>4)+r.
// ---------------------------------------------------------------------------
__global__ __launch_bounds__(256, 2)
void edge_main(const uint4* __restrict__ bpf, const float* __restrict__ hw,
               const float* __restrict__ ef, const float* __restrict__ W1,
               const float* __restrict__ b1, float* __restrict__ out)
{
    __shared__ __align__(16) char slab[SLAB_B];
    const int bx  = blockIdx.x;
    const int ch2 = bx & 1;                   // col-half, constant per XCD parity
    const int eg  = bx >> 1;                  // 0..249
    const int tid = threadIdx.x;
    const int jq  = tid >> 6;                 // j-quarter, 0..3
    const int l   = tid & 63;
    const int l4  = l >> 4;
    const int lm  = l & 15;
    const int e0  = eg * 80;                  // 250*80 = 20000 exact, no masks

    // ---- fused edge-MLP: hidden = relu(ef @ W1 + b1) -> slab fp16 [80][132] ----
    // A: ef rows (K=16 = edge_dim, one MFMA). A-frag: row=l&15, k=4*l4+i.
    // B: W1 cols. Wave jq covers h-cols [32jq, 32jq+32) as two 16-col tiles.
    {
        F4 A[5];
        #pragma unroll
        for (int m = 0; m < 5; ++m) {
            const float4 q4 = *(const float4*)(ef + (size_t)(e0 + 16 * m + lm) * 16 + 4 * l4);
            A[m].h2[0] = (f16x2){(_Float16)q4.x, (_Float16)q4.y};
            A[m].h2[1] = (f16x2){(_Float16)q4.z, (_Float16)q4.w};
        }
        F4 Bw[2];
        float bv[2];
        #pragma unroll
        for (int nn = 0; nn < 2; ++nn) {
            const int col = jq * 32 + nn * 16 + lm;
            float w0 = W1[(4 * l4 + 0) * 128 + col];
            float w1 = W1[(4 * l4 + 1) * 128 + col];
            float w2 = W1[(4 * l4 + 2) * 128 + col];
            float w3 = W1[(4 * l4 + 3) * 128 + col];
            Bw[nn].h2[0] = (f16x2){(_Float16)w0, (_Float16)w1};
            Bw[nn].h2[1] = (f16x2){(_Float16)w2, (_Float16)w3};
            bv[nn] = b1[col];
        }
        #pragma unroll
        for (int m = 0; m < 5; ++m) {
            floatx4 H0 = (floatx4){bv[0], bv[0], bv[0], bv[0]};
            floatx4 H1 = (floatx4){bv[1], bv[1], bv[1], bv[1]};
            H0 = __builtin_amdgcn_mfma_f32_16x16x16f16(A[m].v, Bw[0].v, H0, 0, 0, 0);
            H1 = __builtin_amdgcn_mfma_f32_16x16x16f16(A[m].v, Bw[1].v, H1, 0, 0, 0);
            #pragma unroll
            for (int r = 0; r < 4; ++r) {
                const int e = 16 * m + 4 * l4 + r;          // D: row=4*l4+r, col=lm
                *(unsigned short*)(slab + e * 264 + (jq * 32 + lm) * 2) =
                    f32_to_f16(fmaxf(H0[r], 0.f));
                *(unsigned short*)(slab + e * 264 + (jq * 32 + 16 + lm) * 2) =
                    f32_to_f16(fmaxf(H1[r], 0.f));
            }
        }
        if (tid < 80) {
            *(unsigned int*)(slab + tid * 264 + 256) = 0x00003C00u; // h=128: 1.0, h=129: 0
            *(unsigned int*)(slab + tid * 264 + 260) = 0u;          // h=130,131: 0
        }
    }

    // ---- resident h_w A-source: fp32 load + cast (replaces hwb workspace) ----
    F8 hws[5];
    #pragma unroll
    for (int m = 0; m < 5; ++m) {
        const float* ph = hw + (size_t)(e0 + 16 * m + lm) * 128 + 32 * jq + 8 * l4;
        const float4 x = *(const float4*)ph;
        const float4 y = *(const float4*)(ph + 4);
        hws[m].h2[0] = (f16x2){(_Float16)x.x, (_Float16)x.y};
        hws[m].h2[1] = (f16x2){(_Float16)x.z, (_Float16)x.w};
        hws[m].h2[2] = (f16x2){(_Float16)y.x, (_Float16)y.y};
        hws[m].h2[3] = (f16x2){(_Float16)y.z, (_Float16)y.w};
    }

    floatx4 C[5][4];
    #pragma unroll
    for (int m = 0; m < 5; ++m)
        #pragma unroll
        for (int ct = 0; ct < 4; ++ct)
            C[m][ct] = (floatx4){0.f, 0.f, 0.f, 0.f};

    __syncthreads();    // slab (hidden) complete; only barrier before epilogue

    const f16x8* bpf8 = (const f16x8*)bpf;
    // wave's 16B-chunk base within h-slice; ct offsets {0,64,512,576} cover
    // cols 64*ch2 + 16*ct + lm (ch = 2*ch2 + (ct>>1), nt = ct&1)
    const int cbase = ch2 * 1024 + jq * 128 + l;

    f16x8 B[2][4];
    auto loadB = [&](int h, f16x8 (&Bq)[4]) {
        const f16x8* p = bpf8 + (size_t)h * 2048 + cbase;
        Bq[0] = p[0];
        Bq[1] = p[64];
        Bq[2] = p[512];
        Bq[3] = p[576];                       // 4 x 1KB contiguous per wave
    };
    auto doH = [&](int h, const uint2 (&hid)[5]) {
        const int hh = h & 3, pp = h & 1;
        #pragma unroll
        for (int m = 0; m < 5; ++m) {
            unsigned int s   = (hh < 2) ? hid[m].x : hid[m].y;
            unsigned int sel = (hh & 1) ? 0x03020302u : 0x01000100u;
            f16x2 d = __builtin_bit_cast(f16x2, __builtin_amdgcn_perm(0u, s, sel));
            F8 a;
            #pragma unroll
            for (int i = 0; i < 4; ++i) a.h2[i] = hws[m].h2[i] * d;
            C[m][0] = __builtin_amdgcn_mfma_f32_16x16x32_f16(a.v, B[pp][0], C[m][0], 0, 0, 0);
            C[m][1] = __builtin_amdgcn_mfma_f32_16x16x32_f16(a.v, B[pp][1], C[m][1], 0, 0, 0);
            C[m][2] = __builtin_amdgcn_mfma_f32_16x16x32_f16(a.v, B[pp][2], C[m][2], 0, 0, 0);
            C[m][3] = __builtin_amdgcn_mfma_f32_16x16x32_f16(a.v, B[pp][3], C[m][3], 0, 0, 0);
        }
        loadB(h + 2, B[pp]);                  // refill just-consumed buffer (h+2 <= 133 < 136)
    };

    loadB(0, B[0]);
    loadB(1, B[1]);
    for (int q = 0; q < 33; ++q) {            // h-quad q: h = 4q..4q+3; q=32 = bias+pads
        uint2 hid[5];
        #pragma unroll
        for (int m = 0; m < 5; ++m)           // broadcast ds_read_b64 (l4 ignored)
            hid[m] = *(const uint2*)(slab + (16 * m + lm) * 264 + q * 8);
        doH(4 * q + 0, hid);
        doH(4 * q + 1, hid);
        doH(4 * q + 2, hid);
        doH(4 * q + 3, hid);
    }

    // epilogue: reduce the 4 jq partials in-block via LDS (reuse slab: 20480B),
    // then plain coalesced stores. C/D layout: col = lane&15, row = 4*(lane>>4)+r.
    float* red = (float*)slab;
    #pragma unroll 1
    for (int src = 1; src < 4; ++src) {
        __syncthreads();
        if (jq == src) {
            #pragma unroll
            for (int m = 0; m < 5; ++m)
                #pragma unroll
                for (int ct = 0; ct < 4; ++ct)
                    #pragma unroll
                    for (int r = 0; r < 4; ++r)
                        red[((m * 4 + ct) * 4 + r) * 64 + l] = C[m][ct][r];
        }
        __syncthreads();
        if (jq == 0) {
            #pragma unroll
            for (int m = 0; m < 5; ++m)
                #pragma unroll
                for (int ct = 0; ct < 4; ++ct)
                    #pragma unroll
                    for (int r = 0; r < 4; ++r)
                        C[m][ct][r] += red[((m * 4 + ct) * 4 + r) * 64 + l];
        }
    }
    if (jq == 0) {
        #pragma unroll
        for (int m = 0; m < 5; ++m)
            #pragma unroll
            for (int ct = 0; ct < 4; ++ct)
                #pragma unroll
                for (int r = 0; r < 4; ++r)
                    out[(size_t)(e0 + 16 * m + 4 * l4 + r) * D_DIM
                        + 64 * ch2 + 16 * ct + lm] = C[m][ct][r];
    }
}

// ---------------------------------------------------------------------------
extern "C" void kernel_launch(void* const* d_in, const int* in_sizes, int n_in,
                              void* d_out, int out_size, void* d_ws, size_t ws_size,
                              hipStream_t stream) {
    // inputs: h_v, h_w, edge_features, W1, b1, W2, b2 (fp32; h_v unused)
    const float* h_w = (const float*)d_in[1];
    const float* ef  = (const float*)d_in[2];
    const float* W1  = (const float*)d_in[3];
    const float* b1  = (const float*)d_in[4];
    const float* W2  = (const float*)d_in[5];
    const float* b2  = (const float*)d_in[6];
    float* out = (float*)d_out;

    uint4* bpf = (uint4*)d_ws;   // 136*2048*16 = 4,456,448 B (only workspace user now)

    hipLaunchKernelGGL(prep_w2, dim3(NBA), dim3(256), 0, stream, W2, b2, bpf);
    hipLaunchKernelGGL(edge_main, dim3(500), dim3(256), 0, stream,
                       bpf, h_w, ef, W1, b1, out);
}

// Round 3
// 151.188 us; speedup vs baseline: 1.0821x; 1.0664x over previous
//
#include <hip/hip_runtime.h>

#define E_EDGES 20000
#define D_DIM   128
#define NBA     136       // W2/b2 repack blocks: 128 W2 + 1 bias + 7 zero (prefetch pad)
#define SLAB_B  21504     // per-block hidden slab: 80 edges x 264B (132 h fp16 + pad)

typedef _Float16 f16x8 __attribute__((ext_vector_type(8)));
typedef _Float16 f16x4 __attribute__((ext_vector_type(4)));
typedef _Float16 f16x2 __attribute__((ext_vector_type(2)));
typedef float    floatx4 __attribute__((ext_vector_type(4)));

union F8 { f16x8 v; f16x2 h2[4]; unsigned int u[4]; };
union F4 { f16x4 v; f16x2 h2[2]; unsigned int u[2]; };

__device__ __forceinline__ unsigned short f32_to_f16(float f) {
    _Float16 h = (_Float16)f;
    return __builtin_bit_cast(unsigned short, h);
}

// ---------------------------------------------------------------------------
// prep_w2: repack h-slice of W2 (h==128: b2; h>128: zeros) into fragment-major
// fp16 bpf. cidx = ch*512 + jq*128 + nt*64 + ll; chunk elem j: B_h[k][col],
// col = 32ch+16nt+(ll&15), k = 32jq+8*(ll>>4)+j. One h-slice per block.
// Measured round 2: prep is ~4 us; the remaining ~65 us of "gap" is harness
// restore-dispatch overhead (invariant to our kernels). Leave prep as-is.
// ---------------------------------------------------------------------------
__global__ __launch_bounds__(256) void prep_w2(
    const float* __restrict__ W2, const float* __restrict__ b2,
    uint4* __restrict__ bpf)
{
    __shared__ __align__(16) unsigned short tile[17408];   // [col][136]
    const int h = blockIdx.x;
    const int t = threadIdx.x;

    if (h < 129) {
        const float* src = (h < 128) ? (W2 + (size_t)h * (D_DIM * D_DIM)) : b2;
        #pragma unroll
        for (int r = 0; r < 16; ++r) {
            const float4 v = ((const float4*)src)[r * 256 + t];
            int c   = (r * 256 + t) * 4;
            int col = c >> 7;
            int k   = c & 127;
            unsigned int u0 = f32_to_f16(v.x) | ((unsigned int)f32_to_f16(v.y) << 16);
            unsigned int u1 = f32_to_f16(v.z) | ((unsigned int)f32_to_f16(v.w) << 16);
            *(uint2*)&tile[col * 136 + k] = make_uint2(u0, u1);
        }
        __syncthreads();
        #pragma unroll
        for (int r2 = 0; r2 < 8; ++r2) {
            int cidx = r2 * 256 + t;
            int ll = cidx & 63;
            int nt = (cidx >> 6) & 1;
            int jq = (cidx >> 7) & 3;
            int ch = (cidx >> 9) & 3;
            int col = 32 * ch + 16 * nt + (ll & 15);
            int k0  = 32 * jq + 8 * (ll >> 4);
            bpf[(size_t)h * 2048 + cidx] = *(const uint4*)&tile[col * 136 + k0];
        }
    } else {
        // zero-fill pad slices so prefetch reads never feed NaN garbage into MFMA
        #pragma unroll
        for (int r2 = 0; r2 < 8; ++r2)
            bpf[(size_t)h * 2048 + r2 * 256 + t] = make_uint4(0, 0, 0, 0);
    }
}

// ---------------------------------------------------------------------------
// Main (Z-GEMM v6: deep-ILP): 500 blocks x 256 threads, 2 blocks/CU
// (grid-limited to ~2 waves/SIMD — so each wave gets a 256-VGPR budget and
// must self-hide latency with ILP instead of TLP):
//  - B register prefetch DEPTH 4 (B[4][4], 64 VGPRs): 16 outstanding 16B L2
//    loads per wave ≈ 4 h-steps (~1550 cyc) of latency cover vs ~200-400 cyc
//    L2 latency+queueing. Round 2's dist-2 was the MfmaUtil=40% stall.
//  - hid ds_read double-buffer: next q's 5 broadcast ds_read_b64 issue before
//    the current q's 16 doH MFMA groups -> no lgkmcnt stall at q boundary.
//  - B prologue loads + hw loads issue before the slab barrier.
// Block = 80 edges x 64 cols x 128 j; ch2 = bx&1 is XCD-parity-pinned
// (2.23 MB B slice per XCD L2). Wave = j-quarter jq; per h one A-scale
// (perm + 4 pk_mul per m) feeds 4 MFMAs. Fused prologue: hidden MLP via one
// mfma_f32_16x16x16f16 per (m,nn) into LDS slab; h_w fp32->f16 resident regs.
// Epilogue: jq partials reduced in-block via LDS (reuse slab), coalesced
// stores, no atomics. C/D layout: col = lane&15, row = 4*(lane>>4)+r.
// ---------------------------------------------------------------------------
__global__ __launch_bounds__(256, 2)
void edge_main(const uint4* __restrict__ bpf, const float* __restrict__ hw,
               const float* __restrict__ ef, const float* __restrict__ W1,
               const float* __restrict__ b1, float* __restrict__ out)
{
    __shared__ __align__(16) char slab[SLAB_B];
    const int bx  = blockIdx.x;
    const int ch2 = bx & 1;                   // col-half, constant per XCD parity
    const int eg  = bx >> 1;                  // 0..249
    const int tid = threadIdx.x;
    const int jq  = tid >> 6;                 // j-quarter, 0..3
    const int l   = tid & 63;
    const int l4  = l >> 4;
    const int lm  = l & 15;
    const int e0  = eg * 80;                  // 250*80 = 20000 exact, no masks

    // ---- resident h_w A-source first: issue global loads at kernel entry ----
    F8 hws[5];
    #pragma unroll
    for (int m = 0; m < 5; ++m) {
        const float* ph = hw + (size_t)(e0 + 16 * m + lm) * 128 + 32 * jq + 8 * l4;
        const float4 x = *(const float4*)ph;
        const float4 y = *(const float4*)(ph + 4);
        hws[m].h2[0] = (f16x2){(_Float16)x.x, (_Float16)x.y};
        hws[m].h2[1] = (f16x2){(_Float16)x.z, (_Float16)x.w};
        hws[m].h2[2] = (f16x2){(_Float16)y.x, (_Float16)y.y};
        hws[m].h2[3] = (f16x2){(_Float16)y.z, (_Float16)y.w};
    }

    // ---- fused edge-MLP: hidden = relu(ef @ W1 + b1) -> slab fp16 [80][132] ----
    // A: ef rows (K=16 = edge_dim, one MFMA). A-frag: row=l&15, k=4*l4+i.
    // B: W1 cols. Wave jq covers h-cols [32jq, 32jq+32) as two 16-col tiles.
    {
        F4 A[5];
        #pragma unroll
        for (int m = 0; m < 5; ++m) {
            const float4 q4 = *(const float4*)(ef + (size_t)(e0 + 16 * m + lm) * 16 + 4 * l4);
            A[m].h2[0] = (f16x2){(_Float16)q4.x, (_Float16)q4.y};
            A[m].h2[1] = (f16x2){(_Float16)q4.z, (_Float16)q4.w};
        }
        F4 Bw[2];
        float bv[2];
        #pragma unroll
        for (int nn = 0; nn < 2; ++nn) {
            const int col = jq * 32 + nn * 16 + lm;
            float w0 = W1[(4 * l4 + 0) * 128 + col];
            float w1 = W1[(4 * l4 + 1) * 128 + col];
            float w2 = W1[(4 * l4 + 2) * 128 + col];
            float w3 = W1[(4 * l4 + 3) * 128 + col];
            Bw[nn].h2[0] = (f16x2){(_Float16)w0, (_Float16)w1};
            Bw[nn].h2[1] = (f16x2){(_Float16)w2, (_Float16)w3};
            bv[nn] = b1[col];
        }
        #pragma unroll
        for (int m = 0; m < 5; ++m) {
            floatx4 H0 = (floatx4){bv[0], bv[0], bv[0], bv[0]};
            floatx4 H1 = (floatx4){bv[1], bv[1], bv[1], bv[1]};
            H0 = __builtin_amdgcn_mfma_f32_16x16x16f16(A[m].v, Bw[0].v, H0, 0, 0, 0);
            H1 = __builtin_amdgcn_mfma_f32_16x16x16f16(A[m].v, Bw[1].v, H1, 0, 0, 0);
            #pragma unroll
            for (int r = 0; r < 4; ++r) {
                const int e = 16 * m + 4 * l4 + r;          // D: row=4*l4+r, col=lm
                *(unsigned short*)(slab + e * 264 + (jq * 32 + lm) * 2) =
                    f32_to_f16(fmaxf(H0[r], 0.f));
                *(unsigned short*)(slab + e * 264 + (jq * 32 + 16 + lm) * 2) =
                    f32_to_f16(fmaxf(H1[r], 0.f));
            }
        }
        if (tid < 80) {
            *(unsigned int*)(slab + tid * 264 + 256) = 0x00003C00u; // h=128: 1.0, h=129: 0
            *(unsigned int*)(slab + tid * 264 + 260) = 0u;          // h=130,131: 0
        }
    }

    floatx4 C[5][4];
    #pragma unroll
    for (int m = 0; m < 5; ++m)
        #pragma unroll
        for (int ct = 0; ct < 4; ++ct)
            C[m][ct] = (floatx4){0.f, 0.f, 0.f, 0.f};

    const f16x8* bpf8 = (const f16x8*)bpf;
    // wave's 16B-chunk base within h-slice; ct offsets {0,64,512,576} cover
    // cols 64*ch2 + 16*ct + lm (ch = 2*ch2 + (ct>>1), nt = ct&1)
    const int cbase = ch2 * 1024 + jq * 128 + l;

    f16x8 B[4][4];                            // depth-4 register prefetch
    auto loadB = [&](int h, f16x8 (&Bq)[4]) {
        const f16x8* p = bpf8 + (size_t)h * 2048 + cbase;
        Bq[0] = p[0];
        Bq[1] = p[64];
        Bq[2] = p[512];
        Bq[3] = p[576];                       // 4 x 1KB contiguous per wave
    };
    // issue B prologue (16 loads, L2) BEFORE the slab barrier
    loadB(0, B[0]);
    loadB(1, B[1]);
    loadB(2, B[2]);
    loadB(3, B[3]);

    __syncthreads();    // slab (hidden) complete; only barrier before epilogue

    auto doH = [&](int h, const uint2 (&hid)[5]) {
        const int hh = h & 3;
        #pragma unroll
        for (int m = 0; m < 5; ++m) {
            unsigned int s   = (hh < 2) ? hid[m].x : hid[m].y;
            unsigned int sel = (hh & 1) ? 0x03020302u : 0x01000100u;
            f16x2 d = __builtin_bit_cast(f16x2, __builtin_amdgcn_perm(0u, s, sel));
            F8 a;
            #pragma unroll
            for (int i = 0; i < 4; ++i) a.h2[i] = hws[m].h2[i] * d;
            C[m][0] = __builtin_amdgcn_mfma_f32_16x16x32_f16(a.v, B[hh][0], C[m][0], 0, 0, 0);
            C[m][1] = __builtin_amdgcn_mfma_f32_16x16x32_f16(a.v, B[hh][1], C[m][1], 0, 0, 0);
            C[m][2] = __builtin_amdgcn_mfma_f32_16x16x32_f16(a.v, B[hh][2], C[m][2], 0, 0, 0);
            C[m][3] = __builtin_amdgcn_mfma_f32_16x16x32_f16(a.v, B[hh][3], C[m][3], 0, 0, 0);
        }
        loadB(h + 4, B[hh]);                  // refill just-consumed buffer (h+4 <= 135 < 136)
    };
    auto readHid = [&](int q, uint2 (&hid)[5]) {
        #pragma unroll
        for (int m = 0; m < 5; ++m)           // broadcast ds_read_b64 (l4 ignored)
            hid[m] = *(const uint2*)(slab + (16 * m + lm) * 264 + q * 8);
    };

    uint2 hid0[5], hid1[5];
    readHid(0, hid0);
    #pragma unroll 1
    for (int q = 0; q < 32; q += 2) {         // h-quads q, q+1 (h = 4q .. 4q+7)
        readHid(q + 1, hid1);                 // prefetch next quad's hid
        doH(4 * q + 0, hid0);
        doH(4 * q + 1, hid0);
        doH(4 * q + 2, hid0);
        doH(4 * q + 3, hid0);
        readHid(q + 2, hid0);                 // q+2 <= 32 (q=32 row exists: bias+pads)
        doH(4 * q + 4, hid1);
        doH(4 * q + 5, hid1);
        doH(4 * q + 6, hid1);
        doH(4 * q + 7, hid1);
    }
    // q = 32 tail: h = 128..131 (bias row + zero pads), hid0 read in last iter
    doH(128, hid0);
    doH(129, hid0);
    doH(130, hid0);
    doH(131, hid0);

    // epilogue: reduce the 4 jq partials in-block via LDS (reuse slab: 20480B),
    // then plain coalesced stores. C/D layout: col = lane&15, row = 4*(lane>>4)+r.
    float* red = (float*)slab;
    #pragma unroll 1
    for (int src = 1; src < 4; ++src) {
        __syncthreads();
        if (jq == src) {
            #pragma unroll
            for (int m = 0; m < 5; ++m)
                #pragma unroll
                for (int ct = 0; ct < 4; ++ct)
                    #pragma unroll
                    for (int r = 0; r < 4; ++r)
                        red[((m * 4 + ct) * 4 + r) * 64 + l] = C[m][ct][r];
        }
        __syncthreads();
        if (jq == 0) {
            #pragma unroll
            for (int m = 0; m < 5; ++m)
                #pragma unroll
                for (int ct = 0; ct < 4; ++ct)
                    #pragma unroll
                    for (int r = 0; r < 4; ++r)
                        C[m][ct][r] += red[((m * 4 + ct) * 4 + r) * 64 + l];
        }
    }
    if (jq == 0) {
        #pragma unroll
        for (int m = 0; m < 5; ++m)
            #pragma unroll
            for (int ct = 0; ct < 4; ++ct)
                #pragma unroll
                for (int r = 0; r < 4; ++r)
                    out[(size_t)(e0 + 16 * m + 4 * l4 + r) * D_DIM
                        + 64 * ch2 + 16 * ct + lm] = C[m][ct][r];
    }
}

// ---------------------------------------------------------------------------
extern "C" void kernel_launch(void* const* d_in, const int* in_sizes, int n_in,
                              void* d_out, int out_size, void* d_ws, size_t ws_size,
                              hipStream_t stream) {
    // inputs: h_v, h_w, edge_features, W1, b1, W2, b2 (fp32; h_v unused)
    const float* h_w = (const float*)d_in[1];
    const float* ef  = (const float*)d_in[2];
    const float* W1  = (const float*)d_in[3];
    const float* b1  = (const float*)d_in[4];
    const float* W2  = (const float*)d_in[5];
    const float* b2  = (const float*)d_in[6];
    float* out = (float*)d_out;

    uint4* bpf = (uint4*)d_ws;   // 136*2048*16 = 4,456,448 B (only workspace user now)

    hipLaunchKernelGGL(prep_w2, dim3(NBA), dim3(256), 0, stream, W2, b2, bpf);
    hipLaunchKernelGGL(edge_main, dim3(500), dim3(256), 0, stream,
                       bpf, h_w, ef, W1, b1, out);
}